// Round 4
// baseline (669.219 us; speedup 1.0000x reference)
//
#include <hip/hip_runtime.h>

// SpatialEvoProp — R4: R3's MFMA core + depth-1 software pipeline on edge
// meta. R3 counters: VALUBusy 14.6%, MfmaUtil 3.4%, occ 33% -> latency-bound;
// per-group CU time 5600 cyc vs ~1500 cyc issue work. The serial chain
// idx -> loc -> bucketize -> gathers is pipelined: next group's idx loads
// issue at loop top, next group's loc/degs issue after current gathers.

#define DFEAT 64
#define PPAD 68  // sP row stride (floats): 16B-aligned rows, 8 start banks

typedef __attribute__((ext_vector_type(8))) short short8;
typedef __attribute__((ext_vector_type(4))) float floatx4;

__device__ __forceinline__ short bf16h(float x) {
    unsigned u = __float_as_uint(x);
    return (short)((u + 0x7FFFu + ((u >> 16) & 1u)) >> 16);
}
__device__ __forceinline__ float bf16tof(short h) {
    return __uint_as_float(((unsigned)(unsigned short)h) << 16);
}

// count(boundaries < x): analytic seed + shuffle-verified walk against the
// real table values (lane L holds boundaries[L]); exact (verified R3).
__device__ __forceinline__ int bucketize(float x, float bnd) {
    int i = (int)(x * 31.5f);
    i = min(max(i, 0), 64);
#pragma unroll
    for (int t = 0; t < 3; ++t) {
        float bi = __shfl(bnd, min(i, 63));
        if (i < 64 && bi < x) ++i;
    }
#pragma unroll
    for (int t = 0; t < 2; ++t) {
        float bim = __shfl(bnd, max(i - 1, 0));
        if (i > 0 && bim >= x) --i;
    }
    return i;
}

__global__ void k_init(const float* __restrict__ Etab,
                       const float* __restrict__ G, float* __restrict__ P,
                       float* __restrict__ rst, float* __restrict__ degs,
                       int nRst, int nDeg) {
    int i = blockIdx.x * blockDim.x + threadIdx.x;
    if (i < nRst) rst[i] = 0.0f;
    if (i < nDeg) degs[i] = 0.0f;
    if (i < 65 * DFEAT) {
        int b = i >> 6, o = i & 63;
        float a = 0.0f;
#pragma unroll
        for (int m = 0; m < 32; ++m)
            a = fmaf(Etab[b * 32 + m], G[o * 32 + m], a);
        P[i] = a;
    }
}

__global__ void k_deg(const int* __restrict__ src, const int* __restrict__ dst,
                      float* __restrict__ degs, int N, int E) {
    int i = blockIdx.x * blockDim.x + threadIdx.x;
    if (i < E) {
        atomicAdd(&degs[dst[i]], 1.0f);
        atomicAdd(&degs[N + src[i]], 1.0f);
    }
}

__global__ __launch_bounds__(256, 3) void k_edge(
    const float* __restrict__ feat, const float* __restrict__ loc,
    const float* __restrict__ agg_w, const float* __restrict__ agg_b,
    const float* __restrict__ bnds, const int* __restrict__ src,
    const int* __restrict__ dst, const int* __restrict__ inter,
    const float* __restrict__ P, const float* __restrict__ degs,
    float* __restrict__ rst, int N, int E) {
    const int tid = threadIdx.x;
    const int lane = tid & 63;
    const int wid = tid >> 6;
    const int m16 = lane & 15;
    const int quad = lane >> 4;

    __shared__ alignas(16) float sP[65 * PPAD];  // 17680 B
    __shared__ short8 sWBh[16 * 64];             // 16384 B
    __shared__ short8 sWBl[16 * 64];             // 16384 B

    for (int i = tid; i < 65 * DFEAT; i += 256)
        sP[(i >> 6) * PPAD + (i & 63)] = P[i];

    // B-frag f = slab*4+ntile; lane holds n = nt*16+m16, k = sl*32+quad*8+j
    for (int f = wid; f < 16; f += 4) {
        int sl = f >> 2, nt = f & 3;
        const float* wp = agg_w + (nt * 16 + m16) * 128 + sl * 32 + quad * 8;
        floatx4 wa = *(const floatx4*)wp;
        floatx4 wb = *(const floatx4*)(wp + 4);
        float xs[8] = {wa.x, wa.y, wa.z, wa.w, wb.x, wb.y, wb.z, wb.w};
        short8 h, l;
#pragma unroll
        for (int j = 0; j < 8; ++j) {
            short hh = bf16h(xs[j]);
            h[j] = hh;
            l[j] = bf16h(xs[j] - bf16tof(hh));
        }
        sWBh[f * 64 + lane] = h;
        sWBl[f * 64 + lane] = l;
    }

    const float bnd = bnds[lane];
    float bias4[4];
#pragma unroll
    for (int nt = 0; nt < 4; ++nt) bias4[nt] = agg_b[nt * 16 + m16];

    __syncthreads();

    const int S = gridDim.x << 2;
    const int ngroups = (E + 15) >> 4;
    int g = (blockIdx.x << 2) + wid;
    if (g >= ngroups) return;

    // ---- raw meta for first group (prologue, exposed once) ----------------
    int sC, dC, ijC[5];
    float2 lsC, ldC, ljC[5];
    float dinC, doutC;
    {
        const int em = (g << 4) + m16;
        const int ec = (em < E) ? em : 0;
        sC = src[ec];
        dC = dst[ec];
#pragma unroll
        for (int j = 0; j < 5; ++j) ijC[j] = inter[ec * 5 + j];
        lsC = ((const float2*)loc)[sC];
        ldC = ((const float2*)loc)[dC];
#pragma unroll
        for (int j = 0; j < 5; ++j) ljC[j] = ((const float2*)loc)[ijC[j]];
        dinC = degs[dC];
        doutC = degs[N + sC];
    }

    while (true) {
        const int gn = g + S;
        const bool hasN = gn < ngroups;

        // -- prefetch next group's indices (no dependencies) ----------------
        int sN = 0, dN = 0, ijN[5] = {0, 0, 0, 0, 0};
        if (hasN) {
            const int em = (gn << 4) + m16;
            const int ec = (em < E) ? em : 0;
            sN = src[ec];
            dN = dst[ec];
#pragma unroll
            for (int j = 0; j < 5; ++j) ijN[j] = inter[ec * 5 + j];
        }

        // -- buckets + scale for current (inputs prefetched last iter) ------
        const bool act = ((g << 4) + m16) < E;
        float dsc = rsqrtf(fmaxf(dinC, 1.0f)) * rsqrtf(fmaxf(doutC, 1.0f));
        if (!act) dsc = 0.0f;
        float dx = ldC.x - lsC.x, dy = ldC.y - lsC.y;
        const int b1 = bucketize(sqrtf(dx * dx + dy * dy), bnd);
        int bj[5];
#pragma unroll
        for (int j = 0; j < 5; ++j) {
            float ex = lsC.x - ljC[j].x, ey = lsC.y - ljC[j].y;
            bj[j] = bucketize(sqrtf(ex * ex + ey * ey), bnd);
        }

        // -- build A fragments (the big gather epoch) -----------------------
        short8 Ah[4], Al[4];
        {
            const float* frow = feat + (sC << 6);
            const float* prow = sP + b1 * PPAD;
#pragma unroll
            for (int sl = 0; sl < 2; ++sl) {  // u: cat[k<64]
                int k0 = sl * 32 + quad * 8;
                floatx4 fa = *(const floatx4*)(frow + k0);
                floatx4 fb = *(const floatx4*)(frow + k0 + 4);
                floatx4 pa = *(const floatx4*)(prow + k0);
                floatx4 pb = *(const floatx4*)(prow + k0 + 4);
                float xs[8] = {fa.x * pa.x, fa.y * pa.y, fa.z * pa.z,
                               fa.w * pa.w, fb.x * pb.x, fb.y * pb.y,
                               fb.z * pb.z, fb.w * pb.w};
                short8 h, l;
#pragma unroll
                for (int j = 0; j < 8; ++j) {
                    short hh = bf16h(xs[j]);
                    h[j] = hh;
                    l[j] = bf16h(xs[j] - bf16tof(hh));
                }
                Ah[sl] = h;
                Al[sl] = l;
            }
        }
#pragma unroll
        for (int sl = 0; sl < 2; ++sl) {  // v: cat[k>=64]
            int k0 = sl * 32 + quad * 8;
            float r[8] = {0, 0, 0, 0, 0, 0, 0, 0};
#pragma unroll
            for (int j = 0; j < 5; ++j) {
                const float* fr = feat + (ijC[j] << 6);
                const float* pr = sP + bj[j] * PPAD;
                floatx4 fa = *(const floatx4*)(fr + k0);
                floatx4 fb = *(const floatx4*)(fr + k0 + 4);
                floatx4 pa = *(const floatx4*)(pr + k0);
                floatx4 pb = *(const floatx4*)(pr + k0 + 4);
                r[0] = fmaf(fa.x, pa.x, r[0]);
                r[1] = fmaf(fa.y, pa.y, r[1]);
                r[2] = fmaf(fa.z, pa.z, r[2]);
                r[3] = fmaf(fa.w, pa.w, r[3]);
                r[4] = fmaf(fb.x, pb.x, r[4]);
                r[5] = fmaf(fb.y, pb.y, r[5]);
                r[6] = fmaf(fb.z, pb.z, r[6]);
                r[7] = fmaf(fb.w, pb.w, r[7]);
            }
            short8 h, l;
#pragma unroll
            for (int j = 0; j < 8; ++j) {
                float x = r[j] * 0.2f;
                short hh = bf16h(x);
                h[j] = hh;
                l[j] = bf16h(x - bf16tof(hh));
            }
            Ah[2 + sl] = h;
            Al[2 + sl] = l;
        }

        // -- prefetch next group's loc/degs (idx arrived during A-build) ----
        float2 lsN = {0, 0}, ldN = {0, 0}, ljN[5];
        float dinN = 0, doutN = 0;
        if (hasN) {
            lsN = ((const float2*)loc)[sN];
            ldN = ((const float2*)loc)[dN];
#pragma unroll
            for (int j = 0; j < 5; ++j) ljN[j] = ((const float2*)loc)[ijN[j]];
            dinN = degs[dN];
            doutN = degs[N + sN];
        }

        // -- MFMA: 4 k-slabs x 4 n-tiles x 3 products -----------------------
        floatx4 acc[4] = {{0, 0, 0, 0}, {0, 0, 0, 0}, {0, 0, 0, 0}, {0, 0, 0, 0}};
#pragma unroll
        for (int sl = 0; sl < 4; ++sl) {
#pragma unroll
            for (int nt = 0; nt < 4; ++nt) {
                short8 bh = sWBh[((sl << 2) + nt) * 64 + lane];
                short8 bl = sWBl[((sl << 2) + nt) * 64 + lane];
                acc[nt] = __builtin_amdgcn_mfma_f32_16x16x32_bf16(
                    Ah[sl], bh, acc[nt], 0, 0, 0);
                acc[nt] = __builtin_amdgcn_mfma_f32_16x16x32_bf16(
                    Al[sl], bh, acc[nt], 0, 0, 0);
                acc[nt] = __builtin_amdgcn_mfma_f32_16x16x32_bf16(
                    Ah[sl], bl, acc[nt], 0, 0, 0);
            }
        }

        // -- epilogue: C row = quad*4+r (edge), col = nt*16+m16 (feature) ---
#pragma unroll
        for (int r = 0; r < 4; ++r) {
            const int m = (quad << 2) + r;
            const int dm = __shfl(dC, m);
            const float sc = __shfl(dsc, m);
#pragma unroll
            for (int nt = 0; nt < 4; ++nt) {
                float val = (acc[nt][r] + bias4[nt]) * sc;
                atomicAdd(&rst[(dm << 6) + nt * 16 + m16], val);
            }
        }

        if (!hasN) break;
        // rotate pipeline regs
        sC = sN; dC = dN; lsC = lsN; ldC = ldN; dinC = dinN; doutC = doutN;
#pragma unroll
        for (int j = 0; j < 5; ++j) { ijC[j] = ijN[j]; ljC[j] = ljN[j]; }
        g = gn;
    }
}

extern "C" void kernel_launch(void* const* d_in, const int* in_sizes, int n_in,
                              void* d_out, int out_size, void* d_ws,
                              size_t ws_size, hipStream_t stream) {
    const float* feat  = (const float*)d_in[0];
    const float* loc   = (const float*)d_in[1];
    const float* embed = (const float*)d_in[2];
    const float* G_w   = (const float*)d_in[3];
    const float* agg_w = (const float*)d_in[4];
    const float* agg_b = (const float*)d_in[5];
    const float* bnds  = (const float*)d_in[6];
    const int* src   = (const int*)d_in[7];
    const int* dst   = (const int*)d_in[8];
    const int* inter = (const int*)d_in[9];

    const int N = in_sizes[0] / DFEAT;
    const int E = in_sizes[7];

    float* rst = (float*)d_out;
    float* ws = (float*)d_ws;
    float* degs = ws;               // [2N]
    float* P = ws + 2 * (size_t)N;  // [65*64]

    const int nRst = N * DFEAT;
    const int nDeg = 2 * N;

    k_init<<<(nRst + 255) / 256, 256, 0, stream>>>(embed, G_w, P, rst, degs,
                                                   nRst, nDeg);
    k_deg<<<(E + 255) / 256, 256, 0, stream>>>(src, dst, degs, N, E);
    // LDS 50448 B/block -> 3 blocks/CU; 768 blocks resident
    k_edge<<<768, 256, 0, stream>>>(feat, loc, agg_w, agg_b, bnds, src, dst,
                                    inter, P, degs, rst, N, E);
}

// Round 5
// 423.281 us; speedup vs baseline: 1.5810x; 1.5810x over previous
//
#include <hip/hip_runtime.h>

// SpatialEvoProp — R5: exactly R3's per-wave body (228 µs), but 512-thread
// blocks so the 50.7 KB LDS is amortized over 8 waves instead of 4:
// 3 blocks/CU -> 24 waves/CU (was 12). R4's software pipeline spilled to
// scratch (WRITE 140->780 MB at constant VGPR=84) and is abandoned: this
// compiler spills rather than exceed ~84 VGPRs, so latency hiding must come
// from TLP, not per-wave pipelining.

#define DFEAT 64
#define PPAD 68  // sP row stride (floats): 16B-aligned rows, 8 start banks

typedef __attribute__((ext_vector_type(8))) short short8;
typedef __attribute__((ext_vector_type(4))) float floatx4;

__device__ __forceinline__ short bf16h(float x) {
    unsigned u = __float_as_uint(x);
    return (short)((u + 0x7FFFu + ((u >> 16) & 1u)) >> 16);
}
__device__ __forceinline__ float bf16tof(short h) {
    return __uint_as_float(((unsigned)(unsigned short)h) << 16);
}

// count(boundaries < x): analytic seed + shuffle-verified walk against the
// real table values (lane L holds boundaries[L]); exact (verified R3).
__device__ __forceinline__ int bucketize(float x, float bnd) {
    int i = (int)(x * 31.5f);
    i = min(max(i, 0), 64);
#pragma unroll
    for (int t = 0; t < 3; ++t) {
        float bi = __shfl(bnd, min(i, 63));
        if (i < 64 && bi < x) ++i;
    }
#pragma unroll
    for (int t = 0; t < 2; ++t) {
        float bim = __shfl(bnd, max(i - 1, 0));
        if (i > 0 && bim >= x) --i;
    }
    return i;
}

__global__ void k_init(const float* __restrict__ Etab,
                       const float* __restrict__ G, float* __restrict__ P,
                       float* __restrict__ rst, float* __restrict__ degs,
                       int nRst, int nDeg) {
    int i = blockIdx.x * blockDim.x + threadIdx.x;
    if (i < nRst) rst[i] = 0.0f;
    if (i < nDeg) degs[i] = 0.0f;
    if (i < 65 * DFEAT) {
        int b = i >> 6, o = i & 63;
        float a = 0.0f;
#pragma unroll
        for (int m = 0; m < 32; ++m)
            a = fmaf(Etab[b * 32 + m], G[o * 32 + m], a);
        P[i] = a;
    }
}

__global__ void k_deg(const int* __restrict__ src, const int* __restrict__ dst,
                      float* __restrict__ degs, int N, int E) {
    int i = blockIdx.x * blockDim.x + threadIdx.x;
    if (i < E) {
        atomicAdd(&degs[dst[i]], 1.0f);
        atomicAdd(&degs[N + src[i]], 1.0f);
    }
}

__global__ __launch_bounds__(512, 4) void k_edge(
    const float* __restrict__ feat, const float* __restrict__ loc,
    const float* __restrict__ agg_w, const float* __restrict__ agg_b,
    const float* __restrict__ bnds, const int* __restrict__ src,
    const int* __restrict__ dst, const int* __restrict__ inter,
    const float* __restrict__ P, const float* __restrict__ degs,
    float* __restrict__ rst, int N, int E) {
    const int tid = threadIdx.x;
    const int lane = tid & 63;
    const int wid = tid >> 6;        // 0..7
    const int m16 = lane & 15;
    const int quad = lane >> 4;

    __shared__ alignas(16) float sP[65 * PPAD];  // 17680 B
    __shared__ short8 sWBh[16 * 64];             // 16384 B
    __shared__ short8 sWBl[16 * 64];             // 16384 B

    for (int i = tid; i < 65 * DFEAT; i += 512)
        sP[(i >> 6) * PPAD + (i & 63)] = P[i];

    // B-frag f = slab*4+ntile; lane holds n = nt*16+m16, k = sl*32+quad*8+j
    for (int f = wid; f < 16; f += 8) {
        int sl = f >> 2, nt = f & 3;
        const float* wp = agg_w + (nt * 16 + m16) * 128 + sl * 32 + quad * 8;
        floatx4 wa = *(const floatx4*)wp;
        floatx4 wb = *(const floatx4*)(wp + 4);
        float xs[8] = {wa.x, wa.y, wa.z, wa.w, wb.x, wb.y, wb.z, wb.w};
        short8 h, l;
#pragma unroll
        for (int j = 0; j < 8; ++j) {
            short hh = bf16h(xs[j]);
            h[j] = hh;
            l[j] = bf16h(xs[j] - bf16tof(hh));
        }
        sWBh[f * 64 + lane] = h;
        sWBl[f * 64 + lane] = l;
    }

    const float bnd = bnds[lane];
    float bias4[4];
#pragma unroll
    for (int nt = 0; nt < 4; ++nt) bias4[nt] = agg_b[nt * 16 + m16];

    __syncthreads();

    const int nstream = gridDim.x << 3;           // 8 wave-streams per block
    const int wstream = (blockIdx.x << 3) + wid;
    const int ngroups = (E + 15) >> 4;

    for (int g = wstream; g < ngroups; g += nstream) {
        const int em = (g << 4) + m16;        // this lane's edge (dup x4)
        const bool act = em < E;
        const int ec = act ? em : 0;

        const int s = src[ec];
        const int d = dst[ec];
        const float2 ls = ((const float2*)loc)[s];
        const float2 ld = ((const float2*)loc)[d];
        float dsc = rsqrtf(fmaxf(degs[d], 1.0f)) *
                    rsqrtf(fmaxf(degs[N + s], 1.0f));
        if (!act) dsc = 0.0f;

        float dx = ld.x - ls.x, dy = ld.y - ls.y;
        const int b1 = bucketize(sqrtf(dx * dx + dy * dy), bnd);

        int ij[5], bj[5];
#pragma unroll
        for (int j = 0; j < 5; ++j) {
            int id = inter[ec * 5 + j];
            ij[j] = id;
            float2 lj = ((const float2*)loc)[id];
            float ex = ls.x - lj.x, ey = ls.y - lj.y;
            bj[j] = bucketize(sqrtf(ex * ex + ey * ey), bnd);
        }

        // ---- build A fragments in registers -------------------------------
        short8 Ah[4], Al[4];
        {
            const float* frow = feat + (s << 6);
            const float* prow = sP + b1 * PPAD;
#pragma unroll
            for (int sl = 0; sl < 2; ++sl) {  // u: cat[k<64]
                int k0 = sl * 32 + quad * 8;
                floatx4 fa = *(const floatx4*)(frow + k0);
                floatx4 fb = *(const floatx4*)(frow + k0 + 4);
                floatx4 pa = *(const floatx4*)(prow + k0);
                floatx4 pb = *(const floatx4*)(prow + k0 + 4);
                float xs[8] = {fa.x * pa.x, fa.y * pa.y, fa.z * pa.z,
                               fa.w * pa.w, fb.x * pb.x, fb.y * pb.y,
                               fb.z * pb.z, fb.w * pb.w};
                short8 h, l;
#pragma unroll
                for (int j = 0; j < 8; ++j) {
                    short hh = bf16h(xs[j]);
                    h[j] = hh;
                    l[j] = bf16h(xs[j] - bf16tof(hh));
                }
                Ah[sl] = h;
                Al[sl] = l;
            }
        }
#pragma unroll
        for (int sl = 0; sl < 2; ++sl) {  // v: cat[k>=64]
            int k0 = sl * 32 + quad * 8;
            float r[8] = {0, 0, 0, 0, 0, 0, 0, 0};
#pragma unroll
            for (int j = 0; j < 5; ++j) {
                const float* fr = feat + (ij[j] << 6);
                const float* pr = sP + bj[j] * PPAD;
                floatx4 fa = *(const floatx4*)(fr + k0);
                floatx4 fb = *(const floatx4*)(fr + k0 + 4);
                floatx4 pa = *(const floatx4*)(pr + k0);
                floatx4 pb = *(const floatx4*)(pr + k0 + 4);
                r[0] = fmaf(fa.x, pa.x, r[0]);
                r[1] = fmaf(fa.y, pa.y, r[1]);
                r[2] = fmaf(fa.z, pa.z, r[2]);
                r[3] = fmaf(fa.w, pa.w, r[3]);
                r[4] = fmaf(fb.x, pb.x, r[4]);
                r[5] = fmaf(fb.y, pb.y, r[5]);
                r[6] = fmaf(fb.z, pb.z, r[6]);
                r[7] = fmaf(fb.w, pb.w, r[7]);
            }
            short8 h, l;
#pragma unroll
            for (int j = 0; j < 8; ++j) {
                float x = r[j] * 0.2f;
                short hh = bf16h(x);
                h[j] = hh;
                l[j] = bf16h(x - bf16tof(hh));
            }
            Ah[2 + sl] = h;
            Al[2 + sl] = l;
        }

        // ---- MFMA: 4 k-slabs x 4 n-tiles x 3 products ---------------------
        floatx4 acc[4] = {{0, 0, 0, 0}, {0, 0, 0, 0}, {0, 0, 0, 0}, {0, 0, 0, 0}};
#pragma unroll
        for (int sl = 0; sl < 4; ++sl) {
#pragma unroll
            for (int nt = 0; nt < 4; ++nt) {
                short8 bh = sWBh[((sl << 2) + nt) * 64 + lane];
                short8 bl = sWBl[((sl << 2) + nt) * 64 + lane];
                acc[nt] = __builtin_amdgcn_mfma_f32_16x16x32_bf16(
                    Ah[sl], bh, acc[nt], 0, 0, 0);
                acc[nt] = __builtin_amdgcn_mfma_f32_16x16x32_bf16(
                    Al[sl], bh, acc[nt], 0, 0, 0);
                acc[nt] = __builtin_amdgcn_mfma_f32_16x16x32_bf16(
                    Ah[sl], bl, acc[nt], 0, 0, 0);
            }
        }

        // ---- epilogue: C row = quad*4+r (edge), col = nt*16+m16 (feature) -
#pragma unroll
        for (int r = 0; r < 4; ++r) {
            const int m = (quad << 2) + r;
            const int dm = __shfl(d, m);
            const float sc = __shfl(dsc, m);
#pragma unroll
            for (int nt = 0; nt < 4; ++nt) {
                float val = (acc[nt][r] + bias4[nt]) * sc;
                atomicAdd(&rst[(dm << 6) + nt * 16 + m16], val);
            }
        }
    }
}

extern "C" void kernel_launch(void* const* d_in, const int* in_sizes, int n_in,
                              void* d_out, int out_size, void* d_ws,
                              size_t ws_size, hipStream_t stream) {
    const float* feat  = (const float*)d_in[0];
    const float* loc   = (const float*)d_in[1];
    const float* embed = (const float*)d_in[2];
    const float* G_w   = (const float*)d_in[3];
    const float* agg_w = (const float*)d_in[4];
    const float* agg_b = (const float*)d_in[5];
    const float* bnds  = (const float*)d_in[6];
    const int* src   = (const int*)d_in[7];
    const int* dst   = (const int*)d_in[8];
    const int* inter = (const int*)d_in[9];

    const int N = in_sizes[0] / DFEAT;
    const int E = in_sizes[7];

    float* rst = (float*)d_out;
    float* ws = (float*)d_ws;
    float* degs = ws;               // [2N]
    float* P = ws + 2 * (size_t)N;  // [65*64]

    const int nRst = N * DFEAT;
    const int nDeg = 2 * N;

    k_init<<<(nRst + 255) / 256, 256, 0, stream>>>(embed, G_w, P, rst, degs,
                                                   nRst, nDeg);
    k_deg<<<(E + 255) / 256, 256, 0, stream>>>(src, dst, degs, N, E);
    // 512-thr blocks: LDS 50.7KB/block, 3 blocks/CU -> 24 waves/CU (was 12)
    k_edge<<<768, 512, 0, stream>>>(feat, loc, agg_w, agg_b, bnds, src, dst,
                                    inter, P, degs, rst, N, E);
}